// Round 1
// baseline (59.655 us; speedup 1.0000x reference)
//
#include <hip/hip_runtime.h>
#include <hip/hip_bf16.h>
#include <math.h>

// LNCC: 5 separable 9^3 box filters (f, w, f*f, w*w, f*w), reflect padding,
// pointwise LNCC, global mean -> scalar.
// Volume: B=2, D=H=W=128. N = 4194304 voxels.
//
// Kernel A: per-(b,d)-slice 32x32 tiles; LDS halo 40x40 for f,w; fused W-pass
//           then H-pass for all 5 channels; writes 5*N floats to d_ws.
// Kernel B: D-pass via per-thread 8-deep sliding window + LNCC + block reduce.
// Kernel C: deterministic double reduction -> d_out[0] = -mean.

#define LNCC_EPS 1e-8f
#define NVOX 4194304        // 2*128*128*128
#define SLICE 16384         // 128*128

__device__ __forceinline__ int refl(int p) {
    // reflect (no edge repeat) for dim 128; valid for p in [-127, 254]
    return p < 0 ? -p : (p > 127 ? 254 - p : p);
}

__global__ __launch_bounds__(256)
void lncc_wh_kernel(const float* __restrict__ f, const float* __restrict__ w,
                    float* __restrict__ buf) {
    // grid.x = 256 slices * 16 tiles = 4096
    const int bid   = blockIdx.x;
    const int tile  = bid & 15;          // 4x4 tiles of 32x32
    const int slice = bid >> 4;          // b*128 + d
    const int th0   = (tile >> 2) << 5;
    const int tw0   = (tile & 3) << 5;
    const int tid   = threadIdx.x;

    __shared__ float fs[40][40];
    __shared__ float ws[40][40];
    __shared__ float tmp[5][40][32];

    const float* fsl = f + (size_t)slice * SLICE;
    const float* wsl = w + (size_t)slice * SLICE;

    // load 40x40 halo with reflect indexing
    for (int p = tid; p < 1600; p += 256) {
        int i = p / 40, j = p - i * 40;
        int gh = refl(th0 + i - 4);
        int gw = refl(tw0 + j - 4);
        int g = gh * 128 + gw;
        fs[i][j] = fsl[g];
        ws[i][j] = wsl[g];
    }
    __syncthreads();

    // W-pass: 40 rows x 32 cols, all 5 channels
    for (int p = tid; p < 1280; p += 256) {
        int i = p >> 5, j = p & 31;
        float sf = 0.f, sw = 0.f, sff = 0.f, sww = 0.f, sfw = 0.f;
#pragma unroll
        for (int t = 0; t < 9; ++t) {
            float a = fs[i][j + t];
            float b = ws[i][j + t];
            sf += a; sw += b;
            sff = fmaf(a, a, sff);
            sww = fmaf(b, b, sww);
            sfw = fmaf(a, b, sfw);
        }
        tmp[0][i][j] = sf;  tmp[1][i][j] = sw;
        tmp[2][i][j] = sff; tmp[3][i][j] = sww;
        tmp[4][i][j] = sfw;
    }
    __syncthreads();

    // H-pass: 32x32 outputs, write 5 channels to global
    for (int p = tid; p < 1024; p += 256) {
        int i = p >> 5, j = p & 31;
        size_t oidx = (size_t)slice * SLICE + (size_t)(th0 + i) * 128 + (tw0 + j);
#pragma unroll
        for (int c = 0; c < 5; ++c) {
            float s = 0.f;
#pragma unroll
            for (int t = 0; t < 9; ++t) s += tmp[c][i + t][j];
            buf[(size_t)c * NVOX + oidx] = s;
        }
    }
}

__global__ __launch_bounds__(256)
void lncc_d_kernel(const float* __restrict__ buf, float* __restrict__ partials) {
    // 524288 threads: thread -> (b, dchunk(16), h, w), 8 d-outputs each
    const int gtid = blockIdx.x * 256 + threadIdx.x;
    const int wq = gtid & 127;
    const int h  = (gtid >> 7) & 127;
    const int dc = (gtid >> 14) & 15;
    const int b  = gtid >> 18;
    const int d0 = dc << 3;

    const float inv = 1.0f / 729.0f;
    float s[5][8];

#pragma unroll
    for (int c = 0; c < 5; ++c) {
        const float* bc = buf + (size_t)c * NVOX + (size_t)b * (128 * SLICE)
                        + (size_t)h * 128 + wq;
        float v[16];
#pragma unroll
        for (int t = 0; t < 16; ++t) {
            int d = refl(d0 - 4 + t);
            v[t] = bc[(size_t)d * SLICE];
        }
        float acc = 0.f;
#pragma unroll
        for (int t = 0; t < 9; ++t) acc += v[t];
        s[c][0] = acc;
#pragma unroll
        for (int j = 1; j < 8; ++j) {
            acc += v[j + 8] - v[j - 1];
            s[c][j] = acc;
        }
    }

    float lsum = 0.f;
#pragma unroll
    for (int j = 0; j < 8; ++j) {
        float mf = s[0][j] * inv;
        float mw = s[1][j] * inv;
        float sgf = fmaxf(s[2][j] * inv - mf * mf, LNCC_EPS);
        float sgw = fmaxf(s[3][j] * inv - mw * mw, LNCC_EPS);
        float sfw = s[4][j] * inv - mf * mw;
        float denom = fmaxf(sqrtf(fmaxf(sgf * sgw, LNCC_EPS * LNCC_EPS)), LNCC_EPS);
        float l = sfw / denom;
        l = fminf(fmaxf(l, -10.f), 10.f);
        lsum += l;
    }

    // block reduction: wave shuffle then LDS across 4 waves
#pragma unroll
    for (int off = 32; off > 0; off >>= 1)
        lsum += __shfl_down(lsum, off, 64);
    __shared__ float red[4];
    int lane = threadIdx.x & 63, wid = threadIdx.x >> 6;
    if (lane == 0) red[wid] = lsum;
    __syncthreads();
    if (threadIdx.x == 0)
        partials[blockIdx.x] = red[0] + red[1] + red[2] + red[3];
}

__global__ __launch_bounds__(256)
void lncc_final_kernel(const float* __restrict__ partials, int n,
                       float* __restrict__ out) {
    __shared__ double rd[256];
    double acc = 0.0;
    for (int i = threadIdx.x; i < n; i += 256) acc += (double)partials[i];
    rd[threadIdx.x] = acc;
    __syncthreads();
    for (int s = 128; s > 0; s >>= 1) {
        if (threadIdx.x < s) rd[threadIdx.x] += rd[threadIdx.x + s];
        __syncthreads();
    }
    if (threadIdx.x == 0) out[0] = (float)(-rd[0] / (double)NVOX);
}

extern "C" void kernel_launch(void* const* d_in, const int* in_sizes, int n_in,
                              void* d_out, int out_size, void* d_ws, size_t ws_size,
                              hipStream_t stream) {
    const float* f = (const float*)d_in[0];
    const float* w = (const float*)d_in[1];
    float* out = (float*)d_out;

    float* buf = (float*)d_ws;                       // 5*NVOX floats = 80 MB
    float* partials = buf + (size_t)5 * NVOX;        // 2048 floats

    lncc_wh_kernel<<<4096, 256, 0, stream>>>(f, w, buf);
    lncc_d_kernel<<<2048, 256, 0, stream>>>(buf, partials);
    lncc_final_kernel<<<1, 256, 0, stream>>>(partials, 2048, out);
}

// Round 2
// 53.870 us; speedup vs baseline: 1.1074x; 1.1074x over previous
//
#include <hip/hip_runtime.h>
#include <math.h>

// LNCC, 3-kernel pipeline:
//  A: per-(b,d)-slice 32x32 tiles, LDS halo, W-pass (b128 + register sliding)
//     -> transposed LDS tmp -> H-pass (b128 + sliding) -> u16 fixed-point
//     intermediate (5 ch * NVOX, 40 MB). WH sums are in [0,81] -> x(65535/81).
//  B: D-pass sliding window on u16 (exact in fp32) + LNCC + block reduce.
//  C: deterministic double reduction -> d_out[0] = -mean.

#define NVOX 4194304        // 2*128*128*128
#define SLICE 16384         // 128*128
#define QSCALE (65535.0f / 81.0f)
#define DQ ((float)(81.0 / 65535.0 / 729.0))

__device__ __forceinline__ int refl(int p) {
    // reflect (no edge repeat) for dim 128; valid for p in [-127, 254]
    return p < 0 ? -p : (p > 127 ? 254 - p : p);
}

__global__ __launch_bounds__(256)
void lncc_wh_kernel(const float* __restrict__ f, const float* __restrict__ w,
                    unsigned short* __restrict__ buf) {
    // grid.x = 256 slices * 16 tiles = 4096
    const int bid   = blockIdx.x;
    const int tile  = bid & 15;
    const int slice = bid >> 4;
    const int th0   = (tile >> 2) << 5;
    const int tw0   = (tile & 3) << 5;
    const int tid   = threadIdx.x;

    // row stride 44 floats = 176 B: 16B-aligned rows, distinct bank starts
    __shared__ __align__(16) float fs[40][44];
    __shared__ __align__(16) float ws[40][44];
    __shared__ __align__(16) float tmpT[5][32][44];   // [ch][j][i]

    const float* fsl = f + (size_t)slice * SLICE;
    const float* wsl = w + (size_t)slice * SLICE;

    // stage 40x40 halo with reflect indexing
    for (int p = tid; p < 1600; p += 256) {
        int i = p / 40, j = p - i * 40;
        int g = refl(th0 + i - 4) * 128 + refl(tw0 + j - 4);
        fs[i][j] = fsl[g];
        ws[i][j] = wsl[g];
    }
    __syncthreads();

    // W-pass: 40 rows x 8 j-groups (4-wide) = 320 tasks
    // per task: 6 x ds_read_b128 + register sliding, write transposed tmp
    for (int p = tid; p < 320; p += 256) {
        int i  = p >> 3;
        int j0 = (p & 7) << 2;
        float fv[12], wv[12];
        *(float4*)&fv[0] = *(const float4*)&fs[i][j0];
        *(float4*)&fv[4] = *(const float4*)&fs[i][j0 + 4];
        *(float4*)&fv[8] = *(const float4*)&fs[i][j0 + 8];
        *(float4*)&wv[0] = *(const float4*)&ws[i][j0];
        *(float4*)&wv[4] = *(const float4*)&ws[i][j0 + 4];
        *(float4*)&wv[8] = *(const float4*)&ws[i][j0 + 8];

        float sf = 0.f, sw = 0.f, sff = 0.f, sww = 0.f, sfw = 0.f;
#pragma unroll
        for (int t = 0; t < 9; ++t) {
            sf += fv[t]; sw += wv[t];
            sff = fmaf(fv[t], fv[t], sff);
            sww = fmaf(wv[t], wv[t], sww);
            sfw = fmaf(fv[t], wv[t], sfw);
        }
        tmpT[0][j0][i] = sf;  tmpT[1][j0][i] = sw;
        tmpT[2][j0][i] = sff; tmpT[3][j0][i] = sww; tmpT[4][j0][i] = sfw;
#pragma unroll
        for (int k = 1; k < 4; ++k) {
            float fe = fv[k + 8], fx = fv[k - 1];
            float we = wv[k + 8], wx = wv[k - 1];
            sf += fe - fx; sw += we - wx;
            sff = fmaf(fe, fe, sff); sff = fmaf(-fx, fx, sff);
            sww = fmaf(we, we, sww); sww = fmaf(-wx, wx, sww);
            sfw = fmaf(fe, we, sfw); sfw = fmaf(-fx, wx, sfw);
            tmpT[0][j0 + k][i] = sf;  tmpT[1][j0 + k][i] = sw;
            tmpT[2][j0 + k][i] = sff; tmpT[3][j0 + k][i] = sww;
            tmpT[4][j0 + k][i] = sfw;
        }
    }
    __syncthreads();

    // H-pass: 256 tasks = (j 0..31) x (i-group 0..7, 4-wide), b128 + sliding
    {
        int j  = tid & 31;
        int i0 = (tid >> 5) << 2;
        float acc[5][4];
#pragma unroll
        for (int c = 0; c < 5; ++c) {
            float v[12];
            *(float4*)&v[0] = *(const float4*)&tmpT[c][j][i0];
            *(float4*)&v[4] = *(const float4*)&tmpT[c][j][i0 + 4];
            *(float4*)&v[8] = *(const float4*)&tmpT[c][j][i0 + 8];
            float s = ((v[0] + v[1]) + (v[2] + v[3]))
                    + ((v[4] + v[5]) + (v[6] + v[7])) + v[8];
            acc[c][0] = s;
            s += v[9]  - v[0]; acc[c][1] = s;
            s += v[10] - v[1]; acc[c][2] = s;
            s += v[11] - v[2]; acc[c][3] = s;
        }
        size_t obase = (size_t)slice * SLICE + (size_t)(th0 + i0) * 128 + (tw0 + j);
#pragma unroll
        for (int c = 0; c < 5; ++c)
#pragma unroll
            for (int k = 0; k < 4; ++k)
                buf[(size_t)c * NVOX + obase + (size_t)k * 128] =
                    (unsigned short)fmaf(acc[c][k], QSCALE, 0.5f);
    }
}

__global__ __launch_bounds__(256)
void lncc_d_kernel(const unsigned short* __restrict__ buf,
                   float* __restrict__ partials) {
    // 524288 threads: thread -> (b, dchunk(16), h, w), 8 d-outputs each
    const int gtid = blockIdx.x * 256 + threadIdx.x;
    const int wq = gtid & 127;
    const int h  = (gtid >> 7) & 127;
    const int dc = (gtid >> 14) & 15;
    const int b  = gtid >> 18;
    const int d0 = dc << 3;

    float s[5][8];
#pragma unroll
    for (int c = 0; c < 5; ++c) {
        const unsigned short* bc = buf + (size_t)c * NVOX
                                 + (size_t)b * (128 * SLICE)
                                 + (size_t)h * 128 + wq;
        float v[16];
#pragma unroll
        for (int t = 0; t < 16; ++t) {
            int d = refl(d0 - 4 + t);
            v[t] = (float)bc[(size_t)d * SLICE];
        }
        float acc = 0.f;
#pragma unroll
        for (int t = 0; t < 9; ++t) acc += v[t];
        s[c][0] = acc;
#pragma unroll
        for (int j = 1; j < 8; ++j) {
            acc += v[j + 8] - v[j - 1];
            s[c][j] = acc;
        }
    }

    float lsum = 0.f;
#pragma unroll
    for (int j = 0; j < 8; ++j) {
        float mf = s[0][j] * DQ;
        float mw = s[1][j] * DQ;
        float sgf = fmaxf(s[2][j] * DQ - mf * mf, 1e-8f);
        float sgw = fmaxf(s[3][j] * DQ - mw * mw, 1e-8f);
        float sfw = s[4][j] * DQ - mf * mw;
        float denom = fmaxf(sqrtf(fmaxf(sgf * sgw, 1e-16f)), 1e-8f);
        float l = sfw / denom;
        lsum += fminf(fmaxf(l, -10.f), 10.f);
    }

#pragma unroll
    for (int off = 32; off > 0; off >>= 1)
        lsum += __shfl_down(lsum, off, 64);
    __shared__ float red[4];
    int lane = threadIdx.x & 63, wid = threadIdx.x >> 6;
    if (lane == 0) red[wid] = lsum;
    __syncthreads();
    if (threadIdx.x == 0)
        partials[blockIdx.x] = red[0] + red[1] + red[2] + red[3];
}

__global__ __launch_bounds__(256)
void lncc_final_kernel(const float* __restrict__ partials, int n,
                       float* __restrict__ out) {
    __shared__ double rd[256];
    double acc = 0.0;
    for (int i = threadIdx.x; i < n; i += 256) acc += (double)partials[i];
    rd[threadIdx.x] = acc;
    __syncthreads();
    for (int s = 128; s > 0; s >>= 1) {
        if (threadIdx.x < s) rd[threadIdx.x] += rd[threadIdx.x + s];
        __syncthreads();
    }
    if (threadIdx.x == 0) out[0] = (float)(-rd[0] / (double)NVOX);
}

extern "C" void kernel_launch(void* const* d_in, const int* in_sizes, int n_in,
                              void* d_out, int out_size, void* d_ws, size_t ws_size,
                              hipStream_t stream) {
    const float* f = (const float*)d_in[0];
    const float* w = (const float*)d_in[1];
    float* out = (float*)d_out;

    unsigned short* buf = (unsigned short*)d_ws;              // 5*NVOX u16 = 40 MB
    float* partials = (float*)((char*)d_ws + (size_t)5 * NVOX * 2); // 2048 floats

    lncc_wh_kernel<<<4096, 256, 0, stream>>>(f, w, buf);
    lncc_d_kernel<<<2048, 256, 0, stream>>>(buf, partials);
    lncc_final_kernel<<<1, 256, 0, stream>>>(partials, 2048, out);
}

// Round 3
// 47.328 us; speedup vs baseline: 1.2605x; 1.1382x over previous
//
#include <hip/hip_runtime.h>
#include <math.h>

// LNCC, 3-kernel pipeline:
//  A: per-(b,d)-slice 32x32 tiles. W-pass global->reg (float4 fast path) ->
//     transposed LDS tmp -> H-pass (b128 + sliding) -> u16 fixed-point
//     intermediate (5 ch * NVOX, 40 MB). LDS = tmpT only (27.5 KB) -> 5
//     blocks/CU; 320-thread blocks so the W-pass is 1 task/thread.
//  B: D-pass sliding window on u16 (exact in fp32) + LNCC + block reduce.
//  C: deterministic double reduction -> d_out[0] = -mean.

#define NVOX 4194304        // 2*128*128*128
#define SLICE 16384         // 128*128
#define QSCALE (65535.0f / 81.0f)
#define DQ ((float)(81.0 / 65535.0 / 729.0))

__device__ __forceinline__ int refl(int p) {
    // reflect (no edge repeat) for dim 128; valid for p in [-127, 254]
    return p < 0 ? -p : (p > 127 ? 254 - p : p);
}

__global__ __launch_bounds__(320, 6)
void lncc_wh_kernel(const float* __restrict__ f, const float* __restrict__ w,
                    unsigned short* __restrict__ buf) {
    // grid.x = 256 slices * 16 tiles = 4096
    const int bid   = blockIdx.x;
    const int tile  = bid & 15;
    const int slice = bid >> 4;
    const int th0   = (tile >> 2) << 5;
    const int tw0   = (tile & 3) << 5;
    const int tid   = threadIdx.x;

    __shared__ __align__(16) float tmpT[5][32][44];   // [ch][j][i], i-rows 16B-aligned

    const float* fsl = f + (size_t)slice * SLICE;
    const float* wsl = w + (size_t)slice * SLICE;

    // Phase 1: W-pass. 320 tasks = (i 0..39) x (j-group 0..7, 4-wide), 1/thread.
    {
        const int i  = tid >> 3;
        const int j0 = (tid & 7) << 2;
        const int row = refl(th0 + i - 4);
        const float* frow = fsl + row * 128;
        const float* wrow = wsl + row * 128;
        const int jb = tw0 + j0 - 4;        // multiple of 4

        float fv[12], wv[12];
        if (jb >= 0 && jb <= 116) {         // reflect-free 12-word window
            *(float4*)&fv[0] = *(const float4*)&frow[jb];
            *(float4*)&fv[4] = *(const float4*)&frow[jb + 4];
            *(float4*)&fv[8] = *(const float4*)&frow[jb + 8];
            *(float4*)&wv[0] = *(const float4*)&wrow[jb];
            *(float4*)&wv[4] = *(const float4*)&wrow[jb + 4];
            *(float4*)&wv[8] = *(const float4*)&wrow[jb + 8];
        } else {
#pragma unroll
            for (int t = 0; t < 12; ++t) {
                int c = refl(jb + t);
                fv[t] = frow[c];
                wv[t] = wrow[c];
            }
        }

        float sf = 0.f, sw = 0.f, sff = 0.f, sww = 0.f, sfw = 0.f;
#pragma unroll
        for (int t = 0; t < 9; ++t) {
            sf += fv[t]; sw += wv[t];
            sff = fmaf(fv[t], fv[t], sff);
            sww = fmaf(wv[t], wv[t], sww);
            sfw = fmaf(fv[t], wv[t], sfw);
        }
        tmpT[0][j0][i] = sf;  tmpT[1][j0][i] = sw;
        tmpT[2][j0][i] = sff; tmpT[3][j0][i] = sww; tmpT[4][j0][i] = sfw;
#pragma unroll
        for (int k = 1; k < 4; ++k) {
            float fe = fv[k + 8], fx = fv[k - 1];
            float we = wv[k + 8], wx = wv[k - 1];
            sf += fe - fx; sw += we - wx;
            sff = fmaf(fe, fe, sff); sff = fmaf(-fx, fx, sff);
            sww = fmaf(we, we, sww); sww = fmaf(-wx, wx, sww);
            sfw = fmaf(fe, we, sfw); sfw = fmaf(-fx, wx, sfw);
            tmpT[0][j0 + k][i] = sf;  tmpT[1][j0 + k][i] = sw;
            tmpT[2][j0 + k][i] = sff; tmpT[3][j0 + k][i] = sww;
            tmpT[4][j0 + k][i] = sfw;
        }
    }
    __syncthreads();

    // Phase 2: H-pass. 256 tasks = (j 0..31) x (i-group 0..7, 4-wide).
    if (tid < 256) {
        const int j  = tid & 31;
        const int i0 = (tid >> 5) << 2;
        float acc[5][4];
#pragma unroll
        for (int c = 0; c < 5; ++c) {
            float v[12];
            *(float4*)&v[0] = *(const float4*)&tmpT[c][j][i0];
            *(float4*)&v[4] = *(const float4*)&tmpT[c][j][i0 + 4];
            *(float4*)&v[8] = *(const float4*)&tmpT[c][j][i0 + 8];
            float s = ((v[0] + v[1]) + (v[2] + v[3]))
                    + ((v[4] + v[5]) + (v[6] + v[7])) + v[8];
            acc[c][0] = s;
            s += v[9]  - v[0]; acc[c][1] = s;
            s += v[10] - v[1]; acc[c][2] = s;
            s += v[11] - v[2]; acc[c][3] = s;
        }
        size_t obase = (size_t)slice * SLICE + (size_t)(th0 + i0) * 128 + (tw0 + j);
#pragma unroll
        for (int c = 0; c < 5; ++c)
#pragma unroll
            for (int k = 0; k < 4; ++k)
                buf[(size_t)c * NVOX + obase + (size_t)k * 128] =
                    (unsigned short)fmaf(acc[c][k], QSCALE, 0.5f);
    }
}

__global__ __launch_bounds__(256)
void lncc_d_kernel(const unsigned short* __restrict__ buf,
                   float* __restrict__ partials) {
    // 524288 threads: thread -> (b, dchunk(16), h, w), 8 d-outputs each
    const int gtid = blockIdx.x * 256 + threadIdx.x;
    const int wq = gtid & 127;
    const int h  = (gtid >> 7) & 127;
    const int dc = (gtid >> 14) & 15;
    const int b  = gtid >> 18;
    const int d0 = dc << 3;

    float s[5][8];
#pragma unroll
    for (int c = 0; c < 5; ++c) {
        const unsigned short* bc = buf + (size_t)c * NVOX
                                 + (size_t)b * (128 * SLICE)
                                 + (size_t)h * 128 + wq;
        float v[16];
#pragma unroll
        for (int t = 0; t < 16; ++t) {
            int d = refl(d0 - 4 + t);
            v[t] = (float)bc[(size_t)d * SLICE];
        }
        float acc = 0.f;
#pragma unroll
        for (int t = 0; t < 9; ++t) acc += v[t];
        s[c][0] = acc;
#pragma unroll
        for (int j = 1; j < 8; ++j) {
            acc += v[j + 8] - v[j - 1];
            s[c][j] = acc;
        }
    }

    float lsum = 0.f;
#pragma unroll
    for (int j = 0; j < 8; ++j) {
        float mf = s[0][j] * DQ;
        float mw = s[1][j] * DQ;
        float sgf = fmaxf(s[2][j] * DQ - mf * mf, 1e-8f);
        float sgw = fmaxf(s[3][j] * DQ - mw * mw, 1e-8f);
        float sfw = s[4][j] * DQ - mf * mw;
        float denom = fmaxf(sqrtf(fmaxf(sgf * sgw, 1e-16f)), 1e-8f);
        float l = sfw / denom;
        lsum += fminf(fmaxf(l, -10.f), 10.f);
    }

#pragma unroll
    for (int off = 32; off > 0; off >>= 1)
        lsum += __shfl_down(lsum, off, 64);
    __shared__ float red[4];
    int lane = threadIdx.x & 63, wid = threadIdx.x >> 6;
    if (lane == 0) red[wid] = lsum;
    __syncthreads();
    if (threadIdx.x == 0)
        partials[blockIdx.x] = red[0] + red[1] + red[2] + red[3];
}

__global__ __launch_bounds__(256)
void lncc_final_kernel(const float* __restrict__ partials, int n,
                       float* __restrict__ out) {
    __shared__ double rd[256];
    double acc = 0.0;
    for (int i = threadIdx.x; i < n; i += 256) acc += (double)partials[i];
    rd[threadIdx.x] = acc;
    __syncthreads();
    for (int s = 128; s > 0; s >>= 1) {
        if (threadIdx.x < s) rd[threadIdx.x] += rd[threadIdx.x + s];
        __syncthreads();
    }
    if (threadIdx.x == 0) out[0] = (float)(-rd[0] / (double)NVOX);
}

extern "C" void kernel_launch(void* const* d_in, const int* in_sizes, int n_in,
                              void* d_out, int out_size, void* d_ws, size_t ws_size,
                              hipStream_t stream) {
    const float* f = (const float*)d_in[0];
    const float* w = (const float*)d_in[1];
    float* out = (float*)d_out;

    unsigned short* buf = (unsigned short*)d_ws;              // 5*NVOX u16 = 40 MB
    float* partials = (float*)((char*)d_ws + (size_t)5 * NVOX * 2); // 2048 floats

    lncc_wh_kernel<<<4096, 320, 0, stream>>>(f, w, buf);
    lncc_d_kernel<<<2048, 256, 0, stream>>>(buf, partials);
    lncc_final_kernel<<<1, 256, 0, stream>>>(partials, 2048, out);
}